// Round 3
// baseline (160.296 us; speedup 1.0000x reference)
//
#include <hip/hip_runtime.h>
#include <math.h>

#define NENT 50000
#define NREL 500
#define DIMK 128
#define BATCH 32

// ws layout (floats):
//   [0 .. 8191]      pred re/im interleaved: (b*128+d)*2 + {0:re,1:im}
//   [8192 .. 8223]   pred_r_sum[b]
//   [8224 .. 58223]  u_r_sum[e]  (softplus(ent_rho).sum per entity)
#define WS_PRED 0
#define WS_PSUM 8192
#define WS_URSUM 8224

__device__ __forceinline__ float softplus_f(float x) {
    float e = __expf(-fabsf(x));
    return fmaxf(x, 0.0f) + __logf(1.0f + e);
}

__device__ __forceinline__ float fast_sqrtf(float x) {
#if __has_builtin(__builtin_amdgcn_sqrtf)
    return __builtin_amdgcn_sqrtf(x);
#else
    return sqrtf(x);
#endif
}

// Robust triplet index fetch (int32 or int64 buffer).
__device__ __forceinline__ int get_idx(const void* trip, int flat) {
    const long long* t64 = (const long long*)trip;
    const int* t32 = (const int*)trip;
    bool is64 = true;
    #pragma unroll 1
    for (int i = 0; i < 48; ++i) {
        long long v = t64[i];
        if (v < 0 || v >= NREL) { is64 = false; break; }
    }
    return is64 ? (int)t64[flat] : t32[flat];
}

__global__ __launch_bounds__(128)
void prep_kernel(const float* __restrict__ ent_center,
                 const float* __restrict__ ent_rho,
                 const float* __restrict__ rel_center,
                 const float* __restrict__ rel_rho,
                 const void* __restrict__ trip,
                 float* __restrict__ ws) {
    const int b = blockIdx.x;      // 0..31
    const int d = threadIdx.x;     // 0..127
    const int h = get_idx(trip, b * 3 + 0);
    const int r = get_idx(trip, b * 3 + 1);

    float hre = ent_center[h * 256 + d];
    float him = ent_center[h * 256 + 128 + d];
    float ph  = rel_center[r * 128 + d];
    float s = sinf(ph), c = cosf(ph);
    ws[WS_PRED + (b * 128 + d) * 2 + 0] = hre * c - him * s;
    ws[WS_PRED + (b * 128 + d) * 2 + 1] = hre * s + him * c;

    float pr = softplus_f(ent_rho[h * 128 + d]) + softplus_f(rel_rho[r * 128 + d]);
    #pragma unroll
    for (int off = 32; off > 0; off >>= 1) pr += __shfl_down(pr, off);
    __shared__ float tmp[2];
    if ((threadIdx.x & 63) == 0) tmp[threadIdx.x >> 6] = pr;
    __syncthreads();
    if (threadIdx.x == 0) ws[WS_PSUM + b] = tmp[0] + tmp[1];
}

// u_r_sum pre-pass: one wave per entity, coalesced float2 row read.
__global__ __launch_bounds__(256)
void ursum_kernel(const float* __restrict__ ent_rho, float* __restrict__ ws) {
    const int wave = threadIdx.x >> 6, lane = threadIdx.x & 63;
    const int e = blockIdx.x * 4 + wave;
    if (e >= NENT) return;
    float2 v = *(const float2*)(ent_rho + (size_t)e * 128 + lane * 2);
    float s = softplus_f(v.x) + softplus_f(v.y);
    #pragma unroll
    for (int off = 32; off > 0; off >>= 1) s += __shfl_down(s, off);
    if (lane == 0) ws[WS_URSUM + e] = s;
}

// Block: 256 threads = 4 waves, 64 entities (lane -> entity).
// Wave w owns batches [8w, 8w+8), all 128 dims. No cross-wave reduction.
// Per dq step: group-issue all 18 ds_read_b128 into registers, then compute.
__global__ __launch_bounds__(256, 3)
void score_kernel(const float* __restrict__ ent_center,
                  const float* __restrict__ ws,
                  float* __restrict__ out) {
    __shared__ float4 s_pred[2048];    // 32 KB, fl4 idx = b*64 + d/2 (interleaved re/im)
    __shared__ float4 s_stage[1024];   // 16 KB: slot = (s*8+q)*64 + (et ^ q)

    const int tid = threadIdx.x;
    const int wave = tid >> 6, lane = tid & 63;
    const int e0 = blockIdx.x * 64;
    const int q = tid & 7;          // fl4-within-line index for staging loads
    const int et0 = tid >> 3;       // 0..31, entity-within-block (+32 on round 1)
    const float4* cen4 = (const float4*)ent_center;
    const float4* ws4 = (const float4*)ws;

    // stage pred tile (2048 fl4 / 256 thr = 8 each, coalesced)
    #pragma unroll
    for (int i = 0; i < 8; ++i) s_pred[tid + 256 * i] = ws4[tid + 256 * i];

    float4 g[4];
    auto GLOAD = [&](int c) {
        #pragma unroll
        for (int s = 0; s < 2; ++s)
            #pragma unroll
            for (int r = 0; r < 2; ++r) {
                int ge = e0 + et0 + 32 * r;
                if (ge > NENT - 1) ge = NENT - 1;
                g[s * 2 + r] = cen4[(size_t)ge * 64 + s * 32 + c * 8 + q];
            }
    };
    auto DSWRITE = [&]() {
        #pragma unroll
        for (int s = 0; s < 2; ++s)
            #pragma unroll
            for (int r = 0; r < 2; ++r) {
                int et = et0 + 32 * r;
                s_stage[(s * 8 + q) * 64 + (et ^ q)] = g[s * 2 + r];
            }
    };

    float acc[8];
    #pragma unroll
    for (int b = 0; b < 8; ++b) acc[b] = 0.0f;

    GLOAD(0);
    __syncthreads();                       // pred tile visible
    #pragma unroll 1
    for (int c = 0; c < 4; ++c) {
        if (c) __syncthreads();            // all waves done reading previous chunk
        DSWRITE();                         // (vmcnt auto-wait on g)
        if (c < 3) GLOAD(c + 1);           // issue next chunk early, consumed next iter
        __syncthreads();                   // stage visible
        #pragma unroll
        for (int dq = 0; dq < 8; ++dq) {
            // ---- group-issue ALL LDS reads of this dq step ----
            const float4 ur = s_stage[dq * 64 + (lane ^ dq)];
            const float4 ui = s_stage[(8 + dq) * 64 + (lane ^ dq)];
            float4 P[16];
            #pragma unroll
            for (int bb = 0; bb < 8; ++bb) {
                const int p0 = (wave * 8 + bb) * 64 + c * 16 + dq * 2;
                P[bb * 2 + 0] = s_pred[p0];       // broadcast (conflict-free)
                P[bb * 2 + 1] = s_pred[p0 + 1];
            }
            // ---- register-only compute ----
            #pragma unroll
            for (int bb = 0; bb < 8; ++bb) {
                const float4 p01 = P[bb * 2 + 0];  // re0,im0,re1,im1
                const float4 p23 = P[bb * 2 + 1];  // re2,im2,re3,im3
                float dre, dmi, t;
                dre = p01.x - ur.x; dmi = p01.y - ui.x; t = dre * dre + dmi * dmi; acc[bb] += fast_sqrtf(t);
                dre = p01.z - ur.y; dmi = p01.w - ui.y; t = dre * dre + dmi * dmi; acc[bb] += fast_sqrtf(t);
                dre = p23.x - ur.z; dmi = p23.y - ui.z; t = dre * dre + dmi * dmi; acc[bb] += fast_sqrtf(t);
                dre = p23.z - ur.w; dmi = p23.w - ui.w; t = dre * dre + dmi * dmi; acc[bb] += fast_sqrtf(t);
            }
        }
    }

    const int e = e0 + lane;
    if (e < NENT) {
        const float ursum = ws[WS_URSUM + e];
        #pragma unroll
        for (int bb = 0; bb < 8; ++bb) {
            const int b = wave * 8 + bb;
            out[(size_t)b * NENT + e] = ws[WS_PSUM + b] + ursum - acc[bb];
        }
    }
}

extern "C" void kernel_launch(void* const* d_in, const int* in_sizes, int n_in,
                              void* d_out, int out_size, void* d_ws, size_t ws_size,
                              hipStream_t stream) {
    const float* ent_center = (const float*)d_in[0];
    const float* ent_rho    = (const float*)d_in[1];
    const float* rel_center = (const float*)d_in[2];
    const float* rel_rho    = (const float*)d_in[3];
    const void*  trip       = d_in[4];
    float* ws  = (float*)d_ws;
    float* out = (float*)d_out;

    ursum_kernel<<<(NENT + 3) / 4, 256, 0, stream>>>(ent_rho, ws);
    prep_kernel<<<BATCH, 128, 0, stream>>>(ent_center, ent_rho, rel_center, rel_rho, trip, ws);
    score_kernel<<<(NENT + 63) / 64, 256, 0, stream>>>(ent_center, ws, out);
}